// Round 1
// baseline (1522.219 us; speedup 1.0000x reference)
//
#include <hip/hip_runtime.h>
#include <cstdint>
#include <cstddef>

// Problem constants (B=4, S=2048, K=4096, N=11008, G=128)
#define M_DIM 8192
#define K_DIM 4096
#define N_DIM 11008

typedef short bf16x8 __attribute__((ext_vector_type(8)));
typedef float f32x4  __attribute__((ext_vector_type(4)));
typedef unsigned short us8 __attribute__((ext_vector_type(8)));

__device__ __forceinline__ unsigned short f2bf(float f) {
  // round-to-nearest-even fp32 -> bf16 (no NaN care needed for this data)
  unsigned int u = __float_as_uint(f);
  u += 0x7FFFu + ((u >> 16) & 1u);
  return (unsigned short)(u >> 16);
}

// ---------------- kernel 1: x fp32 -> bf16 ----------------
// M*K = 33,554,432 elems; 8 per thread; grid 16384 x 256 exact.
__global__ __launch_bounds__(256) void cvt_x_kernel(const float* __restrict__ x,
                                                    unsigned short* __restrict__ xb) {
  const int i = blockIdx.x * 256 + threadIdx.x;
  const float4* x4 = (const float4*)x;
  float4 a = x4[(size_t)i * 2];
  float4 b = x4[(size_t)i * 2 + 1];
  us8 o;
  o[0] = f2bf(a.x); o[1] = f2bf(a.y); o[2] = f2bf(a.z); o[3] = f2bf(a.w);
  o[4] = f2bf(b.x); o[5] = f2bf(b.y); o[6] = f2bf(b.z); o[7] = f2bf(b.w);
  *(us8*)(xb + (size_t)i * 8) = o;
}

// ---------------- kernel 2: dequant int4 -> bf16 W^T (N x K) ----------------
// grid: (N/64, K/64) = (172, 64); 64x64 tile per block via LDS transpose.
__global__ __launch_bounds__(256) void dequant_kernel(const int* __restrict__ qw,
                                                      const float* __restrict__ sc,
                                                      unsigned short* __restrict__ wt) {
  const int n0 = blockIdx.x * 64;
  const int k0 = blockIdx.y * 64;
  const int g  = blockIdx.y >> 1;     // group = k0/128 (uniform: 64-tile never crosses a 128 group)
  __shared__ unsigned short lds[64 * 64];   // [n_local][k_local]
  const int t = threadIdx.x;

  // Load+unpack: 512 ints (8 qweight rows x 64 cols), 2 per thread, coalesced int2.
  {
    const int kk_l = t >> 5;            // 0..7 (qweight row within tile)
    const int n_l  = (t & 31) * 2;      // 0..62
    const int2  q2 = *(const int2*)&qw[(k0 / 8 + kk_l) * N_DIM + n0 + n_l];
    const float2 s2 = *(const float2*)&sc[g * N_DIM + n0 + n_l];
    us8 o0, o1;
#pragma unroll
    for (int j = 0; j < 8; ++j) {
      o0[j] = f2bf((float)(((q2.x >> (4 * j)) & 15) - 8) * s2.x);
      o1[j] = f2bf((float)(((q2.y >> (4 * j)) & 15) - 8) * s2.y);
    }
    *(us8*)&lds[(n_l    ) * 64 + kk_l * 8] = o0;
    *(us8*)&lds[(n_l + 1) * 64 + kk_l * 8] = o1;
  }
  __syncthreads();
  // Write out: W^T row n gets 64 consecutive k as 16B chunks, coalesced.
#pragma unroll
  for (int it = 0; it < 2; ++it) {
    const int idx = t + it * 256;       // 0..511
    const int n_l = idx >> 3;
    const int ch  = (idx & 7) * 8;
    *(us8*)&wt[(size_t)(n0 + n_l) * K_DIM + k0 + ch] = *(const us8*)&lds[n_l * 64 + ch];
  }
}

// ---------------- kernel 3: bf16 MFMA GEMM (m97 structure) ----------------
// A: (M,K) bf16 row-major. Bt: (N,K) bf16 row-major. C: (M,N) fp32.
// 128x128 tile, BK=64, 4 waves (2x2), each wave 64x64 = 4x4 mfma_f32_16x16x32_bf16.
__global__ __launch_bounds__(256) void gemm_kernel(const unsigned short* __restrict__ A,
                                                   const unsigned short* __restrict__ Bt,
                                                   float* __restrict__ C) {
  __shared__ unsigned short sA[128 * 64];
  __shared__ unsigned short sB[128 * 64];
  const int t    = threadIdx.x;
  const int wave = t >> 6;
  const int lane = t & 63;
  const int wr   = wave >> 1;   // wave row (0..1)
  const int wc   = wave & 1;    // wave col (0..1)
  const int m0   = blockIdx.y * 128;
  const int n0   = blockIdx.x * 128;

  // Staging addresses: thread t covers LDS elems [8t, 8t+8) per issue i (+2048i),
  // i.e. tile row t/8 + 32i, cols 8*(t%8)..+7. Matches global_load_lds lane*16 rule.
  const unsigned short* gA = A  + (size_t)(m0 + (t >> 3)) * K_DIM + (t & 7) * 8;
  const unsigned short* gB = Bt + (size_t)(n0 + (t >> 3)) * K_DIM + (t & 7) * 8;

  f32x4 acc[4][4] = {};

  for (int k0 = 0; k0 < K_DIM; k0 += 64) {
#pragma unroll
    for (int i = 0; i < 4; ++i) {
      __builtin_amdgcn_global_load_lds(
          (const __attribute__((address_space(1))) unsigned int*)(gA + (size_t)i * 32 * K_DIM + k0),
          (__attribute__((address_space(3))) unsigned int*)(&sA[i * 2048 + t * 8]),
          16, 0, 0);
      __builtin_amdgcn_global_load_lds(
          (const __attribute__((address_space(1))) unsigned int*)(gB + (size_t)i * 32 * K_DIM + k0),
          (__attribute__((address_space(3))) unsigned int*)(&sB[i * 2048 + t * 8]),
          16, 0, 0);
    }
    __syncthreads();

#pragma unroll
    for (int ks = 0; ks < 2; ++ks) {
      const int kc = ks * 32 + (lane >> 4) * 8;   // A[m][k]: m=lane&15, k=quad*8+j
      bf16x8 a[4], b[4];
#pragma unroll
      for (int i = 0; i < 4; ++i) {
        a[i] = *(const bf16x8*)&sA[(wr * 64 + i * 16 + (lane & 15)) * 64 + kc];
        b[i] = *(const bf16x8*)&sB[(wc * 64 + i * 16 + (lane & 15)) * 64 + kc];
      }
#pragma unroll
      for (int mi = 0; mi < 4; ++mi)
#pragma unroll
        for (int ni = 0; ni < 4; ++ni)
          acc[mi][ni] = __builtin_amdgcn_mfma_f32_16x16x32_bf16(a[mi], b[ni], acc[mi][ni], 0, 0, 0);
    }
    __syncthreads();
  }

  // Epilogue. C/D layout: col = lane&15, row = (lane>>4)*4 + reg.
  const int cn = n0 + wc * 64 + (lane & 15);
  const int rm = m0 + wr * 64 + (lane >> 4) * 4;
#pragma unroll
  for (int mi = 0; mi < 4; ++mi)
#pragma unroll
    for (int ni = 0; ni < 4; ++ni)
#pragma unroll
      for (int r = 0; r < 4; ++r)
        C[(size_t)(rm + mi * 16 + r) * N_DIM + cn + ni * 16] = acc[mi][ni][r];
}

extern "C" void kernel_launch(void* const* d_in, const int* in_sizes, int n_in,
                              void* d_out, int out_size, void* d_ws, size_t ws_size,
                              hipStream_t stream) {
  const float* x  = (const float*)d_in[0];
  const int*   qw = (const int*)d_in[1];
  const float* sc = (const float*)d_in[2];
  // d_in[3] = group_size (128, hard-coded)
  float* out = (float*)d_out;

  unsigned short* xb = (unsigned short*)d_ws;                                   // 64 MB
  unsigned short* wt = (unsigned short*)((char*)d_ws + (size_t)M_DIM * K_DIM * 2); // +86 MB

  cvt_x_kernel<<<dim3(M_DIM * K_DIM / (8 * 256)), dim3(256), 0, stream>>>(x, xb);
  dequant_kernel<<<dim3(N_DIM / 64, K_DIM / 64), dim3(256), 0, stream>>>(qw, sc, wt);
  gemm_kernel<<<dim3(N_DIM / 128, M_DIM / 128), dim3(256), 0, stream>>>(xb, wt, out);
}